// Round 15
// baseline (502.076 us; speedup 1.0000x reference)
//
#include <hip/hip_runtime.h>
#include <math.h>

#define B_ 16
#define CIN_ 3
#define HID_ 64
#define S_ 16384
#define MODES_ 16
#define HEADS_ 4
#define CH_ 16
#define ED_ 8
#define NPSP_ 500
#define NPFR_ 200
#define LAYERS_ 4
#define RECW_ 34                      // per-channel packed record, FLOATS (R13):
                                      // [0..31] mode AB pairs, [32] w0*sp_b[c], [33] w0

// gelu in f32: rounding to f32 at gelu INPUT == where the reference's own f32
// pipeline sits; h-store is f32 anyway. erff ~2ulp. Hash-path stays f64.
__device__ __forceinline__ float gelu_f32(float v) {
    return 0.5f * v * (1.0f + erff(v * 0.70710678118654752f));
}

// cos(m*pi/32), sin(m*pi/32), m = 0..15
__device__ __constant__ double KC_[16] = {1.0, 0.99518472667219688624,
    0.98078528040323044913, 0.95694033573220886494, 0.92387953251128675613,
    0.88192126434835502971, 0.83146961230254523708, 0.77301045336273696081,
    0.70710678118654752440, 0.63439328416364549822, 0.55557023301960222474,
    0.47139673682599764856, 0.38268343236508977173, 0.29028467725446236764,
    0.19509032201612826785, 0.09801714032956060199};
__device__ __constant__ double KS_[16] = {0.0, 0.09801714032956060199,
    0.19509032201612826785, 0.29028467725446236764, 0.38268343236508977173,
    0.47139673682599764856, 0.55557023301960222474, 0.63439328416364549822,
    0.70710678118654752440, 0.77301045336273696081, 0.83146961230254523708,
    0.88192126434835502971, 0.92387953251128675613, 0.95694033573220886494,
    0.98078528040323044913, 0.99518472667219688624};

// ---------------------------------------------------------------------------
// Spatial table: T0f[lay][c][id] = sum_e sp_emb[lay][id][e] * sp_W[lay][e][c].
// ---------------------------------------------------------------------------
__global__ __launch_bounds__(256) void k_sptab(const float* __restrict__ sp_emb,
                                               const float* __restrict__ sp_W,
                                               float* __restrict__ T0f) {
    int lay = blockIdx.y;
    int tid = blockIdx.x * 256 + threadIdx.x;   // [0, 32000) = 500*64
    int c = tid & 63, id = tid >> 6;
    const float* e = sp_emb + (size_t)lay * NPSP_ * ED_ + (size_t)id * ED_;
    const float* w = sp_W + (size_t)lay * ED_ * HID_ + c;
    double a = 0.0;
#pragma unroll
    for (int k = 0; k < ED_; k++) a = fma((double)e[k], (double)w[k * HID_], a);
    T0f[((size_t)lay * HID_ + c) * NPSP_ + id] = (float)a;
}

// ---------------------------------------------------------------------------
// Lift: h[b,d,s] = sum_c x[b,c,s]*W[c,d] + bias[d].  Channel-sum written as
// FOUR partials (d-quarters) matching k_recon's z=4 channel split.
// ---------------------------------------------------------------------------
__global__ __launch_bounds__(256) void k_lift(const float* __restrict__ x,
                                              const float* __restrict__ W,
                                              const float* __restrict__ bias,
                                              float* __restrict__ h,
                                              double* __restrict__ sC2) {
    int b = blockIdx.y;
    int s = blockIdx.x * 256 + threadIdx.x;
    const float* xb = x + (size_t)b * CIN_ * S_ + s;
    double x0 = (double)xb[0];
    double x1 = (double)xb[S_];
    double x2 = (double)xb[2 * S_];
    float* hb = h + (size_t)b * HID_ * S_ + s;
#pragma unroll
    for (int q = 0; q < 4; ++q) {
        double a = 0.0;
        for (int dd = 0; dd < 16; ++dd) {
            int d = q * 16 + dd;
            double v = x0 * (double)W[d];
            v = fma(x1, (double)W[HID_ + d], v);
            v = fma(x2, (double)W[2 * HID_ + d], v);
            v += (double)bias[d];
            hb[(size_t)d * S_] = (float)v;
            a += v;
        }
        sC2[(size_t)(q * B_ + b) * S_ + s] = a;
    }
}

// ---------------------------------------------------------------------------
// Spatial hash: wsum window over (sC2 q0+q1+q2+q3), idx, block-reduced
// embedding sum (Eb).
// ---------------------------------------------------------------------------
__global__ __launch_bounds__(256) void k_hash(const double* __restrict__ sC2,
                                              const float* __restrict__ emb_l,
                                              int* __restrict__ idx,
                                              double* __restrict__ Eb) {
    int b = blockIdx.y;
    int s0 = blockIdx.x * 256;
    int t = threadIdx.x;
    __shared__ double sl[260];
    for (int j = t; j < 260; j += 256) {
        int p = s0 - 2 + j;
        p = p < 0 ? 0 : (p > S_ - 1 ? S_ - 1 : p);
        const double* sb = sC2 + (size_t)b * S_ + p;
        sl[j] = ((sb[0] + sb[(size_t)B_ * S_]) + sb[(size_t)2 * B_ * S_])
                + sb[(size_t)3 * B_ * S_];
    }
    __syncthreads();
    double wsum = ((sl[t] + sl[t + 1]) + sl[t + 2]) + sl[t + 3];
    int ti = (int)(wsum * 31.0);
    int id = ti % NPSP_;
    if (id < 0) id += NPSP_;
    idx[(size_t)b * S_ + s0 + t] = id;

    const float* er = emb_l + id * ED_;
    double ev[8];
#pragma unroll
    for (int k = 0; k < 8; k++) ev[k] = (double)er[k];

    int lane = t & 63, wv = t >> 6;
    __shared__ double red[4][8];
#pragma unroll
    for (int k = 0; k < 8; k++) {
        double v = ev[k];
        for (int off = 32; off > 0; off >>= 1) v += __shfl_down(v, off, 64);
        if (lane == 0) red[wv][k] = v;
    }
    __syncthreads();
    if (t < 8) {
        double v = red[0][t] + red[1][t] + red[2][t] + red[3][t];
        atomicAdd(&Eb[b * ED_ + t], v);
    }
}

// ---------------------------------------------------------------------------
// 16-mode DFT, radix-4 decimation.
// R15 shape (1 channel x 8 modes, twiddle recurrence, bit-exact).
// R20: unroll 2 on k-loop = WIN (-2 us/dispatch, no spill).
// R21: unroll 4 — 16 loads in flight; est ~105 VGPR < 128 cap. Bit-exact
// (each acc[j]'s k-sequence unchanged). Tripwire: WRITE_SIZE balloon = spill
// -> revert. DO NOT raise waves/EU (R19: (256,8) squeezed alloc to 32 VGPR
// -> 1.5 GB scratch spill). DO NOT const-fold twiddles (R16/R17: f64 consts
// can't be VOP3 inline operands -> register-pair pressure -> spill).
// ---------------------------------------------------------------------------
__global__ __launch_bounds__(256, 4) void k_dft(const float* __restrict__ h,
                                                double* __restrict__ Xr,
                                                double* __restrict__ Xi) {
    int b = blockIdx.y;
    int c0 = blockIdx.x >> 1;
    int mlo = (blockIdx.x & 1) * 8;
    int t = threadIdx.x;
    const float* h0 = h + ((size_t)(b * HID_ + c0)) * S_ + t;

    double acc[16];
#pragma unroll
    for (int k = 0; k < 16; k++) acc[k] = 0.0;

    double c1 = cospi((double)t / 8192.0);
    double s1 = sinpi((double)t / 8192.0);
    double cmv[8], smv[8];
    {
        double cc_ = 1.0, ss_ = 0.0;            // m = 0
        for (int j = 0; j < mlo; j++) {         // advance to m = mlo (0 or 8)
            double nc = cc_ * c1 - ss_ * s1;
            double ns = ss_ * c1 + cc_ * s1;
            cc_ = nc; ss_ = ns;
        }
#pragma unroll
        for (int mi = 0; mi < 8; mi++) {
            cmv[mi] = cc_; smv[mi] = ss_;
            double nc = cc_ * c1 - ss_ * s1;
            double ns = ss_ * c1 + cc_ * s1;
            cc_ = nc; ss_ = ns;
        }
    }

#pragma unroll 4
    for (int k = 0; k < 16; k++) {
        int s = k << 8;
        double a0 = (double)h0[s];
        double b0 = (double)h0[s + 4096];
        double c0v = (double)h0[s + 8192];
        double d0 = (double)h0[s + 12288];

        double t10 = a0 + c0v, t20 = b0 + d0;
        double g00 = t10 + t20, g20 = t10 - t20;
        double ar0 = a0 - c0v, br0 = b0 - d0;

        if (mlo == 0) {                         // DC mode lives in half 0
            acc[0] += g00;
        }
#pragma unroll
        for (int mi = 0; mi < 8; mi++) {
            if (mlo == 0 && mi == 0) continue;  // handled above
            double c = cmv[mi], s_ = smv[mi];
            if ((mi & 1) == 0) {
                double g0x = (mi & 2) ? g20 : g00;
                acc[mi]     = fma(g0x, c,  acc[mi]);
                acc[8 + mi] = fma(g0x, s_, acc[8 + mi]);
            } else if ((mi & 2) == 0) {
                acc[mi]     = fma(ar0, c,  fma(-br0, s_, acc[mi]));
                acc[8 + mi] = fma(ar0, s_, fma( br0, c,  acc[8 + mi]));
            } else {
                acc[mi]     = fma(ar0, c,  fma( br0, s_, acc[mi]));
                acc[8 + mi] = fma(ar0, s_, fma(-br0, c,  acc[8 + mi]));
            }
        }
#pragma unroll
        for (int mi = 0; mi < 8; mi++) {
            int m = mlo + mi;
            double cn = cmv[mi] * KC_[m] - smv[mi] * KS_[m];
            double sn = smv[mi] * KC_[m] + cmv[mi] * KS_[m];
            cmv[mi] = cn; smv[mi] = sn;
        }
    }

    int lane = t & 63, wv = t >> 6;
    __shared__ double red[4][16];
#pragma unroll
    for (int k = 0; k < 16; k++) {
        double v = acc[k];
        for (int off = 32; off > 0; off >>= 1) v += __shfl_down(v, off, 64);
        if (lane == 0) red[wv][k] = v;
    }
    __syncthreads();
    if (t < 16) {
        double v = ((red[0][t] + red[1][t]) + red[2][t]) + red[3][t];
        int im = t >> 3, mi = t & 7;
        size_t o = ((size_t)b * HID_ + c0) * MODES_ + mlo + mi;
        if (im) Xi[o] = -v;
        else    Xr[o] = v;
    }
}

// ---------------------------------------------------------------------------
// Gate/pack with fused MX.  R13: REC packed as FLOAT (recon consumes f32);
// all internal arithmetic unchanged (f64), only the final stores cast.
//   REC[b][c][0..31] = AB pairs: {k_m*(w1*MX_r+w2*P), m? -k_m*w1*MX_i : 0}
//   REC[b][c][32]    = w0*sp_b[c];  REC[b][c][33] = w0
// (NB: the 46 us k_gate rows in R14's profile are a cold-L2 replay artifact
// — 0.3% VALUBusy, 0.34% HBM; real in-run cost ~12 us by budget arithmetic.)
// ---------------------------------------------------------------------------
__global__ __launch_bounds__(256) void k_gate(const double* __restrict__ Xr,
                                              const double* __restrict__ Xi,
                                              const float* __restrict__ mWr,
                                              const float* __restrict__ mWi,
                                              const float* __restrict__ fr_emb_l,
                                              const float* __restrict__ fr_W_l,
                                              const float* __restrict__ fr_b_l,
                                              const double* __restrict__ Eb,
                                              const float* __restrict__ sp_W_l,
                                              const float* __restrict__ sp_b_l,
                                              const float* __restrict__ gW1,
                                              const float* __restrict__ gb1,
                                              const float* __restrict__ gW2,
                                              const float* __restrict__ gb2,
                                              float* __restrict__ RECg) {
    int b = blockIdx.x;
    int t = threadIdx.x;
    __shared__ double sXr[1024], sXi[1024];
    __shared__ double sMr[1024], sMi[1024], sP[1024];
    __shared__ double gg[192], h1s[64], sww[3];
    __shared__ int magI[MODES_];
    __shared__ int fidxS;

    for (int j = t; j < 1024; j += 256) {
        sXr[j] = Xr[(size_t)b * 1024 + j];
        sXi[j] = Xi[(size_t)b * 1024 + j];
    }
    __syncthreads();

    if (t < MODES_) {
        double acc = 0.0;
        for (int c = 0; c < HID_; c++) {
            double re = sXr[c * MODES_ + t];
            double im = sXi[c * MODES_ + t];
            acc += sqrt(re * re + im * im);
        }
        magI[t] = (int)(acc * (1.0 / 64.0) * 1000.0);
    }

    for (int u = t; u < 1024; u += 256) {
        int hh = u >> 8, rem = u & 255, o = rem >> 4, m = rem & 15;
        const float* wr = mWr + (size_t)hh * CH_ * CH_ * MODES_;
        const float* wi = mWi + (size_t)hh * CH_ * CH_ * MODES_;
        double aR = 0.0, aI = 0.0;
#pragma unroll 4
        for (int i = 0; i < CH_; i++) {
            double xrv = sXr[(hh * CH_ + i) * MODES_ + m];
            double xiv = sXi[(hh * CH_ + i) * MODES_ + m];
            double wrv = (double)wr[(i * CH_ + o) * MODES_ + m];
            double wiv = (double)wi[(i * CH_ + o) * MODES_ + m];
            aR += xrv * wrv - xiv * wiv;
            aI += xrv * wiv + xiv * wrv;
        }
        sMr[(hh * CH_ + o) * MODES_ + m] = aR;
        sMi[(hh * CH_ + o) * MODES_ + m] = aI;
    }
    __syncthreads();

    if (t == 0) {
        int ssum = 0;
        for (int m = 0; m < MODES_; m++) ssum += magI[m];
        int f = ssum % NPFR_;
        if (f < 0) f += NPFR_;
        fidxS = f;
    }
    __syncthreads();

    {
        const float* fe = fr_emb_l + fidxS * ED_;
        for (int u = t; u < 1024; u += 256) {
            double acc = 0.0;
            for (int e = 0; e < ED_; e++)
                acc += (double)fe[e] * (double)fr_W_l[e * 1024 + u];
            sP[u] = acc + (double)fr_b_l[u];
        }
    }
    __syncthreads();

    if (t < 64) {
        double a = 0.0;
        for (int e = 0; e < ED_; e++)
            a += Eb[b * ED_ + e] * (double)sp_W_l[e * 64 + t];
        gg[t]       = a * (1.0 / 16384.0) + (double)sp_b_l[t];
        gg[64 + t]  = sMr[t * MODES_] * (1.0 / 16384.0);
        gg[128 + t] = sP[t * MODES_] * (1.0 / 16384.0);
    }
    __syncthreads();
    if (t < 64) {
        double a = 0.0;
        for (int k = 0; k < 192; k++) a += gg[k] * (double)gW1[k * 64 + t];
        a += (double)gb1[t];
        h1s[t] = a > 0.0 ? a : 0.0;
    }
    __syncthreads();
    if (t == 0) {
        double l[3];
        for (int j = 0; j < 3; j++) {
            double a = 0.0;
            for (int k = 0; k < 64; k++) a += h1s[k] * (double)gW2[k * 3 + j];
            l[j] = a + (double)gb2[j];
        }
        double mx = fmax(l[0], fmax(l[1], l[2]));
        double e0 = exp(l[0] - mx), e1 = exp(l[1] - mx), e2 = exp(l[2] - mx);
        double sum = e0 + e1 + e2;
        sww[0] = e0 / sum; sww[1] = e1 / sum; sww[2] = e2 / sum;
    }
    __syncthreads();

    double w0s = sww[0], w1s = sww[1], w2s = sww[2];
    float* R = RECg + (size_t)b * HID_ * RECW_;
    for (int u = t; u < 1024; u += 256) {
        int c = u >> 4, m = u & 15;
        double km = (m == 0 ? 1.0 : 2.0) * (1.0 / 16384.0);
        R[c * RECW_ + 2 * m]     = (float)(km * (w1s * sMr[u] + w2s * sP[u]));
        R[c * RECW_ + 2 * m + 1] = (m == 0) ? 0.0f : (float)(-(km * w1s * sMi[u]));
    }
    if (t < 64) {
        R[t * RECW_ + 32] = (float)(w0s * (double)sp_b_l[t]);
        R[t * RECW_ + 33] = (float)w0s;
    }
}

// ---------------------------------------------------------------------------
// Reconstruction: QUARTET positions (s, s+4096, s+8192, s+12288) per thread.
// R14 shape: f32 datapath, 4 blocks/CU (proven small win, bit-stable).
// ---------------------------------------------------------------------------
__global__ __launch_bounds__(256, 4) void k_recon(const int* __restrict__ idx,
                                                  const float* __restrict__ T0f_l,
                                                  const float* __restrict__ RECg,
                                                  float* __restrict__ h,
                                                  double* __restrict__ sC2) {
    int b = blockIdx.y;
    int cz = blockIdx.z;                       // 0..3, 16 channels each
    int cbase = cz * 16;
    int s0 = blockIdx.x * 256 + threadIdx.x;   // [0, 4096)
    int t = threadIdx.x;
    __shared__ __align__(16) float sT[16 * NPSP_];   // 31.25 KB
    {
        const float4* src = reinterpret_cast<const float4*>(T0f_l + (size_t)cbase * NPSP_);
        float4* dst = reinterpret_cast<float4*>(sT);
        for (int j = t; j < 16 * NPSP_ / 4; j += 256) dst[j] = src[j];
    }
    __syncthreads();

    int id0 = idx[(size_t)b * S_ + s0];
    int id1 = idx[(size_t)b * S_ + s0 + 4096];
    int id2 = idx[(size_t)b * S_ + s0 + 8192];
    int id3 = idx[(size_t)b * S_ + s0 + 12288];

    double cb = cospi((double)s0 / 8192.0);
    double sb = sinpi((double)s0 / 8192.0);
    double cmd = 1.0, smd = 0.0;
    float cm[16], sm[16];
    cm[0] = 1.0f; sm[0] = 0.0f;
#pragma unroll
    for (int m = 1; m < 16; m++) {
        double nc = cmd * cb - smd * sb;
        double ns = smd * cb + cmd * sb;
        cmd = nc; smd = ns;
        cm[m] = (float)cmd; sm[m] = (float)smd;
    }

    const float* Rb = RECg + ((size_t)b * HID_ + cbase) * RECW_;
    float w0g = Rb[33];
    float* hb = h + (size_t)b * HID_ * S_ + (size_t)cbase * S_;
    double cs0 = 0.0, cs1 = 0.0, cs2 = 0.0, cs3 = 0.0;
#pragma unroll 2
    for (int c = 0; c < 16; c++) {
        const float2* r2 = (const float2*)(Rb + (size_t)c * RECW_);
        const float* tc = sT + c * NPSP_;
        float bias = Rb[(size_t)c * RECW_ + 32];
        float p0 = fmaf(w0g, tc[id0], bias);
        float p1 = fmaf(w0g, tc[id1], bias);
        float p2 = fmaf(w0g, tc[id2], bias);
        float p3 = fmaf(w0g, tc[id3], bias);
        float PA = 0.0f, PB = 0.0f, PC = 0.0f, PD = 0.0f, QB = 0.0f, QD = 0.0f;
#pragma unroll
        for (int mm = 0; mm < 16; mm += 4) {
            float2 q0 = r2[mm], q1 = r2[mm + 1], q2 = r2[mm + 2], q3 = r2[mm + 3];
            PA = fmaf(q0.x, cm[mm], PA);     PA = fmaf(q0.y, sm[mm], PA);
            PB = fmaf(q1.x, cm[mm + 1], PB); PB = fmaf(q1.y, sm[mm + 1], PB);
            QB = fmaf(q1.y, cm[mm + 1], QB); QB = fmaf(-q1.x, sm[mm + 1], QB);
            PC = fmaf(q2.x, cm[mm + 2], PC); PC = fmaf(q2.y, sm[mm + 2], PC);
            PD = fmaf(q3.x, cm[mm + 3], PD); PD = fmaf(q3.y, sm[mm + 3], PD);
            QD = fmaf(q3.y, cm[mm + 3], QD); QD = fmaf(-q3.x, sm[mm + 3], QD);
        }
        float u0 = PA + PC, u1 = PA - PC;
        float w0 = PB + PD, qd = QB - QD;
        float g0 = gelu_f32(p0 + (u0 + w0));
        float g1 = gelu_f32(p1 + (u1 + qd));
        float g2 = gelu_f32(p2 + (u0 - w0));
        float g3 = gelu_f32(p3 + (u1 - qd));
        hb[(size_t)c * S_ + s0]         = g0;
        hb[(size_t)c * S_ + s0 + 4096]  = g1;
        hb[(size_t)c * S_ + s0 + 8192]  = g2;
        hb[(size_t)c * S_ + s0 + 12288] = g3;
        cs0 += (double)g0; cs1 += (double)g1;
        cs2 += (double)g2; cs3 += (double)g3;
    }
    double* sc = sC2 + (size_t)(cz * B_ + b) * S_;
    sc[s0]         = cs0;
    sc[s0 + 4096]  = cs1;
    sc[s0 + 8192]  = cs2;
    sc[s0 + 12288] = cs3;
}

// ---------------------------------------------------------------------------
// Projection: out[b,s] = sum_d h[b,d,s]*pW[d] + pb
// ---------------------------------------------------------------------------
__global__ __launch_bounds__(256) void k_proj(const float* __restrict__ h,
                                              const float* __restrict__ pW,
                                              const float* __restrict__ pb,
                                              float* __restrict__ out) {
    int b = blockIdx.y;
    int s = blockIdx.x * 256 + threadIdx.x;
    const float* hb = h + (size_t)b * HID_ * S_ + s;
    double acc = 0.0;
    for (int d = 0; d < HID_; d++)
        acc += (double)hb[(size_t)d * S_] * (double)pW[d];
    out[(size_t)b * S_ + s] = (float)(acc + (double)pb[0]);
}

extern "C" void kernel_launch(void* const* d_in, const int* in_sizes, int n_in,
                              void* d_out, int out_size, void* d_ws, size_t ws_size,
                              hipStream_t stream) {
    const float* x      = (const float*)d_in[0];
    const float* lift_W = (const float*)d_in[1];
    const float* lift_b = (const float*)d_in[2];
    const float* proj_W = (const float*)d_in[3];
    const float* proj_b = (const float*)d_in[4];
    const float* sp_emb = (const float*)d_in[5];
    const float* sp_W   = (const float*)d_in[6];
    const float* sp_b   = (const float*)d_in[7];
    const float* fr_emb = (const float*)d_in[8];
    const float* fr_W   = (const float*)d_in[9];
    const float* fr_b   = (const float*)d_in[10];
    const float* g_W1   = (const float*)d_in[11];
    const float* g_b1   = (const float*)d_in[12];
    const float* g_W2   = (const float*)d_in[13];
    const float* g_b2   = (const float*)d_in[14];
    const float* mhf_Wr = (const float*)d_in[15];
    const float* mhf_Wi = (const float*)d_in[16];

    char* ws = (char*)d_ws;
    float* h    = (float*)ws;   ws += (size_t)B_ * HID_ * S_ * 4;   // 64 MiB
    double* sC2 = (double*)ws;  ws += (size_t)4 * B_ * S_ * 8;      // 8 MiB (4 slices)
    int* idx    = (int*)ws;     ws += (size_t)B_ * S_ * 4;          // 1 MiB
    double* Xr  = (double*)ws;  ws += (size_t)B_ * HID_ * MODES_ * 8;
    double* Xi  = (double*)ws;  ws += (size_t)B_ * HID_ * MODES_ * 8;
    float* REC  = (float*)ws;   ws += (size_t)B_ * HID_ * RECW_ * 4;
    double* Eb  = (double*)ws;  ws += (size_t)LAYERS_ * B_ * ED_ * 8;
    float* T0f  = (float*)ws;   ws += (size_t)LAYERS_ * HID_ * NPSP_ * 4;  // 500 KiB

    hipMemsetAsync(Eb, 0, (size_t)LAYERS_ * B_ * ED_ * 8, stream);

    dim3 blk(256);
    k_sptab<<<dim3(NPSP_ * HID_ / 256, LAYERS_), blk, 0, stream>>>(sp_emb, sp_W, T0f);
    k_lift<<<dim3(S_ / 256, B_), blk, 0, stream>>>(x, lift_W, lift_b, h, sC2);

    for (int lay = 0; lay < LAYERS_; ++lay) {
        k_hash<<<dim3(S_ / 256, B_), blk, 0, stream>>>(
            sC2, sp_emb + (size_t)lay * NPSP_ * ED_, idx, Eb + (size_t)lay * B_ * ED_);
        k_dft<<<dim3(HID_ * 2, B_), blk, 0, stream>>>(h, Xr, Xi);
        k_gate<<<dim3(B_), blk, 0, stream>>>(
            Xr, Xi,
            mhf_Wr + (size_t)lay * HEADS_ * CH_ * CH_ * MODES_,
            mhf_Wi + (size_t)lay * HEADS_ * CH_ * CH_ * MODES_,
            fr_emb + (size_t)lay * NPFR_ * ED_,
            fr_W + (size_t)lay * ED_ * HID_ * MODES_,
            fr_b + (size_t)lay * HID_ * MODES_,
            Eb + (size_t)lay * B_ * ED_,
            sp_W + (size_t)lay * ED_ * HID_,
            sp_b + (size_t)lay * HID_,
            g_W1 + (size_t)lay * 192 * 64,
            g_b1 + (size_t)lay * 64,
            g_W2 + (size_t)lay * 64 * 3,
            g_b2 + (size_t)lay * 3,
            REC);
        k_recon<<<dim3(S_ / 1024, B_, 4), blk, 0, stream>>>(
            idx, T0f + (size_t)lay * HID_ * NPSP_, REC, h, sC2);
    }

    k_proj<<<dim3(S_ / 256, B_), blk, 0, stream>>>(h, proj_W, proj_b, (float*)d_out);
}

// Round 16
// 479.558 us; speedup vs baseline: 1.0470x; 1.0470x over previous
//
#include <hip/hip_runtime.h>
#include <math.h>

#define B_ 16
#define CIN_ 3
#define HID_ 64
#define S_ 16384
#define MODES_ 16
#define HEADS_ 4
#define CH_ 16
#define ED_ 8
#define NPSP_ 500
#define NPFR_ 200
#define LAYERS_ 4
#define RECW_ 34                      // per-channel packed record, FLOATS (R13):
                                      // [0..31] mode AB pairs, [32] w0*sp_b[c], [33] w0

// gelu in f32: rounding to f32 at gelu INPUT == where the reference's own f32
// pipeline sits; h-store is f32 anyway. erff ~2ulp. Hash-path stays f64.
__device__ __forceinline__ float gelu_f32(float v) {
    return 0.5f * v * (1.0f + erff(v * 0.70710678118654752f));
}

// cos(m*pi/32), sin(m*pi/32), m = 0..15
__device__ __constant__ double KC_[16] = {1.0, 0.99518472667219688624,
    0.98078528040323044913, 0.95694033573220886494, 0.92387953251128675613,
    0.88192126434835502971, 0.83146961230254523708, 0.77301045336273696081,
    0.70710678118654752440, 0.63439328416364549822, 0.55557023301960222474,
    0.47139673682599764856, 0.38268343236508977173, 0.29028467725446236764,
    0.19509032201612826785, 0.09801714032956060199};
__device__ __constant__ double KS_[16] = {0.0, 0.09801714032956060199,
    0.19509032201612826785, 0.29028467725446236764, 0.38268343236508977173,
    0.47139673682599764856, 0.55557023301960222474, 0.63439328416364549822,
    0.70710678118654752440, 0.77301045336273696081, 0.83146961230254523708,
    0.88192126434835502971, 0.92387953251128675613, 0.95694033573220886494,
    0.98078528040323044913, 0.99518472667219688624};

// ---------------------------------------------------------------------------
// Spatial table: T0f[lay][c][id] = sum_e sp_emb[lay][id][e] * sp_W[lay][e][c].
// ---------------------------------------------------------------------------
__global__ __launch_bounds__(256) void k_sptab(const float* __restrict__ sp_emb,
                                               const float* __restrict__ sp_W,
                                               float* __restrict__ T0f) {
    int lay = blockIdx.y;
    int tid = blockIdx.x * 256 + threadIdx.x;   // [0, 32000) = 500*64
    int c = tid & 63, id = tid >> 6;
    const float* e = sp_emb + (size_t)lay * NPSP_ * ED_ + (size_t)id * ED_;
    const float* w = sp_W + (size_t)lay * ED_ * HID_ + c;
    double a = 0.0;
#pragma unroll
    for (int k = 0; k < ED_; k++) a = fma((double)e[k], (double)w[k * HID_], a);
    T0f[((size_t)lay * HID_ + c) * NPSP_ + id] = (float)a;
}

// ---------------------------------------------------------------------------
// Lift: h[b,d,s] = sum_c x[b,c,s]*W[c,d] + bias[d].  Channel-sum written as
// FOUR partials (d-quarters) matching k_recon's z=4 channel split.
// ---------------------------------------------------------------------------
__global__ __launch_bounds__(256) void k_lift(const float* __restrict__ x,
                                              const float* __restrict__ W,
                                              const float* __restrict__ bias,
                                              float* __restrict__ h,
                                              double* __restrict__ sC2) {
    int b = blockIdx.y;
    int s = blockIdx.x * 256 + threadIdx.x;
    const float* xb = x + (size_t)b * CIN_ * S_ + s;
    double x0 = (double)xb[0];
    double x1 = (double)xb[S_];
    double x2 = (double)xb[2 * S_];
    float* hb = h + (size_t)b * HID_ * S_ + s;
#pragma unroll
    for (int q = 0; q < 4; ++q) {
        double a = 0.0;
        for (int dd = 0; dd < 16; ++dd) {
            int d = q * 16 + dd;
            double v = x0 * (double)W[d];
            v = fma(x1, (double)W[HID_ + d], v);
            v = fma(x2, (double)W[2 * HID_ + d], v);
            v += (double)bias[d];
            hb[(size_t)d * S_] = (float)v;
            a += v;
        }
        sC2[(size_t)(q * B_ + b) * S_ + s] = a;
    }
}

// ---------------------------------------------------------------------------
// Spatial hash: wsum window over (sC2 q0+q1+q2+q3), idx, block-reduced
// embedding sum (Eb).
// ---------------------------------------------------------------------------
__global__ __launch_bounds__(256) void k_hash(const double* __restrict__ sC2,
                                              const float* __restrict__ emb_l,
                                              int* __restrict__ idx,
                                              double* __restrict__ Eb) {
    int b = blockIdx.y;
    int s0 = blockIdx.x * 256;
    int t = threadIdx.x;
    __shared__ double sl[260];
    for (int j = t; j < 260; j += 256) {
        int p = s0 - 2 + j;
        p = p < 0 ? 0 : (p > S_ - 1 ? S_ - 1 : p);
        const double* sb = sC2 + (size_t)b * S_ + p;
        sl[j] = ((sb[0] + sb[(size_t)B_ * S_]) + sb[(size_t)2 * B_ * S_])
                + sb[(size_t)3 * B_ * S_];
    }
    __syncthreads();
    double wsum = ((sl[t] + sl[t + 1]) + sl[t + 2]) + sl[t + 3];
    int ti = (int)(wsum * 31.0);
    int id = ti % NPSP_;
    if (id < 0) id += NPSP_;
    idx[(size_t)b * S_ + s0 + t] = id;

    const float* er = emb_l + id * ED_;
    double ev[8];
#pragma unroll
    for (int k = 0; k < 8; k++) ev[k] = (double)er[k];

    int lane = t & 63, wv = t >> 6;
    __shared__ double red[4][8];
#pragma unroll
    for (int k = 0; k < 8; k++) {
        double v = ev[k];
        for (int off = 32; off > 0; off >>= 1) v += __shfl_down(v, off, 64);
        if (lane == 0) red[wv][k] = v;
    }
    __syncthreads();
    if (t < 8) {
        double v = red[0][t] + red[1][t] + red[2][t] + red[3][t];
        atomicAdd(&Eb[b * ED_ + t], v);
    }
}

// ---------------------------------------------------------------------------
// 16-mode DFT, radix-4 decimation.
// R15 shape (1 channel x 8 modes, twiddle recurrence, bit-exact).
// R20: #pragma unroll 2 on k-loop = CHAMPION (485.4 us total). R21's
// unroll 4 REGRESSED (+17 us: register-pressure cliff) — unroll 2 is the
// sweet spot. DO NOT raise waves/EU (R19: (256,8) squeezed alloc to 32 VGPR
// -> 1.5 GB scratch spill, 880 us). DO NOT const-fold twiddles (R16/R17:
// f64 consts can't be VOP3 inline operands -> register pressure -> spill).
// ---------------------------------------------------------------------------
__global__ __launch_bounds__(256, 4) void k_dft(const float* __restrict__ h,
                                                double* __restrict__ Xr,
                                                double* __restrict__ Xi) {
    int b = blockIdx.y;
    int c0 = blockIdx.x >> 1;
    int mlo = (blockIdx.x & 1) * 8;
    int t = threadIdx.x;
    const float* h0 = h + ((size_t)(b * HID_ + c0)) * S_ + t;

    double acc[16];
#pragma unroll
    for (int k = 0; k < 16; k++) acc[k] = 0.0;

    double c1 = cospi((double)t / 8192.0);
    double s1 = sinpi((double)t / 8192.0);
    double cmv[8], smv[8];
    {
        double cc_ = 1.0, ss_ = 0.0;            // m = 0
        for (int j = 0; j < mlo; j++) {         // advance to m = mlo (0 or 8)
            double nc = cc_ * c1 - ss_ * s1;
            double ns = ss_ * c1 + cc_ * s1;
            cc_ = nc; ss_ = ns;
        }
#pragma unroll
        for (int mi = 0; mi < 8; mi++) {
            cmv[mi] = cc_; smv[mi] = ss_;
            double nc = cc_ * c1 - ss_ * s1;
            double ns = ss_ * c1 + cc_ * s1;
            cc_ = nc; ss_ = ns;
        }
    }

#pragma unroll 2
    for (int k = 0; k < 16; k++) {
        int s = k << 8;
        double a0 = (double)h0[s];
        double b0 = (double)h0[s + 4096];
        double c0v = (double)h0[s + 8192];
        double d0 = (double)h0[s + 12288];

        double t10 = a0 + c0v, t20 = b0 + d0;
        double g00 = t10 + t20, g20 = t10 - t20;
        double ar0 = a0 - c0v, br0 = b0 - d0;

        if (mlo == 0) {                         // DC mode lives in half 0
            acc[0] += g00;
        }
#pragma unroll
        for (int mi = 0; mi < 8; mi++) {
            if (mlo == 0 && mi == 0) continue;  // handled above
            double c = cmv[mi], s_ = smv[mi];
            if ((mi & 1) == 0) {
                double g0x = (mi & 2) ? g20 : g00;
                acc[mi]     = fma(g0x, c,  acc[mi]);
                acc[8 + mi] = fma(g0x, s_, acc[8 + mi]);
            } else if ((mi & 2) == 0) {
                acc[mi]     = fma(ar0, c,  fma(-br0, s_, acc[mi]));
                acc[8 + mi] = fma(ar0, s_, fma( br0, c,  acc[8 + mi]));
            } else {
                acc[mi]     = fma(ar0, c,  fma( br0, s_, acc[mi]));
                acc[8 + mi] = fma(ar0, s_, fma(-br0, c,  acc[8 + mi]));
            }
        }
#pragma unroll
        for (int mi = 0; mi < 8; mi++) {
            int m = mlo + mi;
            double cn = cmv[mi] * KC_[m] - smv[mi] * KS_[m];
            double sn = smv[mi] * KC_[m] + cmv[mi] * KS_[m];
            cmv[mi] = cn; smv[mi] = sn;
        }
    }

    int lane = t & 63, wv = t >> 6;
    __shared__ double red[4][16];
#pragma unroll
    for (int k = 0; k < 16; k++) {
        double v = acc[k];
        for (int off = 32; off > 0; off >>= 1) v += __shfl_down(v, off, 64);
        if (lane == 0) red[wv][k] = v;
    }
    __syncthreads();
    if (t < 16) {
        double v = ((red[0][t] + red[1][t]) + red[2][t]) + red[3][t];
        int im = t >> 3, mi = t & 7;
        size_t o = ((size_t)b * HID_ + c0) * MODES_ + mlo + mi;
        if (im) Xi[o] = -v;
        else    Xr[o] = v;
    }
}

// ---------------------------------------------------------------------------
// Gate/pack with fused MX.  R13: REC packed as FLOAT (recon consumes f32);
// all internal arithmetic unchanged (f64), only the final stores cast.
//   REC[b][c][0..31] = AB pairs: {k_m*(w1*MX_r+w2*P), m? -k_m*w1*MX_i : 0}
//   REC[b][c][32]    = w0*sp_b[c];  REC[b][c][33] = w0
// (NB: the 46 us k_gate rows in R14's profile are a cold-L2 replay artifact
// — 0.3% VALUBusy, 0.34% HBM; real in-run cost ~12 us by budget arithmetic.)
// ---------------------------------------------------------------------------
__global__ __launch_bounds__(256) void k_gate(const double* __restrict__ Xr,
                                              const double* __restrict__ Xi,
                                              const float* __restrict__ mWr,
                                              const float* __restrict__ mWi,
                                              const float* __restrict__ fr_emb_l,
                                              const float* __restrict__ fr_W_l,
                                              const float* __restrict__ fr_b_l,
                                              const double* __restrict__ Eb,
                                              const float* __restrict__ sp_W_l,
                                              const float* __restrict__ sp_b_l,
                                              const float* __restrict__ gW1,
                                              const float* __restrict__ gb1,
                                              const float* __restrict__ gW2,
                                              const float* __restrict__ gb2,
                                              float* __restrict__ RECg) {
    int b = blockIdx.x;
    int t = threadIdx.x;
    __shared__ double sXr[1024], sXi[1024];
    __shared__ double sMr[1024], sMi[1024], sP[1024];
    __shared__ double gg[192], h1s[64], sww[3];
    __shared__ int magI[MODES_];
    __shared__ int fidxS;

    for (int j = t; j < 1024; j += 256) {
        sXr[j] = Xr[(size_t)b * 1024 + j];
        sXi[j] = Xi[(size_t)b * 1024 + j];
    }
    __syncthreads();

    if (t < MODES_) {
        double acc = 0.0;
        for (int c = 0; c < HID_; c++) {
            double re = sXr[c * MODES_ + t];
            double im = sXi[c * MODES_ + t];
            acc += sqrt(re * re + im * im);
        }
        magI[t] = (int)(acc * (1.0 / 64.0) * 1000.0);
    }

    for (int u = t; u < 1024; u += 256) {
        int hh = u >> 8, rem = u & 255, o = rem >> 4, m = rem & 15;
        const float* wr = mWr + (size_t)hh * CH_ * CH_ * MODES_;
        const float* wi = mWi + (size_t)hh * CH_ * CH_ * MODES_;
        double aR = 0.0, aI = 0.0;
#pragma unroll 4
        for (int i = 0; i < CH_; i++) {
            double xrv = sXr[(hh * CH_ + i) * MODES_ + m];
            double xiv = sXi[(hh * CH_ + i) * MODES_ + m];
            double wrv = (double)wr[(i * CH_ + o) * MODES_ + m];
            double wiv = (double)wi[(i * CH_ + o) * MODES_ + m];
            aR += xrv * wrv - xiv * wiv;
            aI += xrv * wiv + xiv * wrv;
        }
        sMr[(hh * CH_ + o) * MODES_ + m] = aR;
        sMi[(hh * CH_ + o) * MODES_ + m] = aI;
    }
    __syncthreads();

    if (t == 0) {
        int ssum = 0;
        for (int m = 0; m < MODES_; m++) ssum += magI[m];
        int f = ssum % NPFR_;
        if (f < 0) f += NPFR_;
        fidxS = f;
    }
    __syncthreads();

    {
        const float* fe = fr_emb_l + fidxS * ED_;
        for (int u = t; u < 1024; u += 256) {
            double acc = 0.0;
            for (int e = 0; e < ED_; e++)
                acc += (double)fe[e] * (double)fr_W_l[e * 1024 + u];
            sP[u] = acc + (double)fr_b_l[u];
        }
    }
    __syncthreads();

    if (t < 64) {
        double a = 0.0;
        for (int e = 0; e < ED_; e++)
            a += Eb[b * ED_ + e] * (double)sp_W_l[e * 64 + t];
        gg[t]       = a * (1.0 / 16384.0) + (double)sp_b_l[t];
        gg[64 + t]  = sMr[t * MODES_] * (1.0 / 16384.0);
        gg[128 + t] = sP[t * MODES_] * (1.0 / 16384.0);
    }
    __syncthreads();
    if (t < 64) {
        double a = 0.0;
        for (int k = 0; k < 192; k++) a += gg[k] * (double)gW1[k * 64 + t];
        a += (double)gb1[t];
        h1s[t] = a > 0.0 ? a : 0.0;
    }
    __syncthreads();
    if (t == 0) {
        double l[3];
        for (int j = 0; j < 3; j++) {
            double a = 0.0;
            for (int k = 0; k < 64; k++) a += h1s[k] * (double)gW2[k * 3 + j];
            l[j] = a + (double)gb2[j];
        }
        double mx = fmax(l[0], fmax(l[1], l[2]));
        double e0 = exp(l[0] - mx), e1 = exp(l[1] - mx), e2 = exp(l[2] - mx);
        double sum = e0 + e1 + e2;
        sww[0] = e0 / sum; sww[1] = e1 / sum; sww[2] = e2 / sum;
    }
    __syncthreads();

    double w0s = sww[0], w1s = sww[1], w2s = sww[2];
    float* R = RECg + (size_t)b * HID_ * RECW_;
    for (int u = t; u < 1024; u += 256) {
        int c = u >> 4, m = u & 15;
        double km = (m == 0 ? 1.0 : 2.0) * (1.0 / 16384.0);
        R[c * RECW_ + 2 * m]     = (float)(km * (w1s * sMr[u] + w2s * sP[u]));
        R[c * RECW_ + 2 * m + 1] = (m == 0) ? 0.0f : (float)(-(km * w1s * sMi[u]));
    }
    if (t < 64) {
        R[t * RECW_ + 32] = (float)(w0s * (double)sp_b_l[t]);
        R[t * RECW_ + 33] = (float)w0s;
    }
}

// ---------------------------------------------------------------------------
// Reconstruction: QUARTET positions (s, s+4096, s+8192, s+12288) per thread.
// R14 shape: f32 datapath, 4 blocks/CU (proven small win, bit-stable).
// ---------------------------------------------------------------------------
__global__ __launch_bounds__(256, 4) void k_recon(const int* __restrict__ idx,
                                                  const float* __restrict__ T0f_l,
                                                  const float* __restrict__ RECg,
                                                  float* __restrict__ h,
                                                  double* __restrict__ sC2) {
    int b = blockIdx.y;
    int cz = blockIdx.z;                       // 0..3, 16 channels each
    int cbase = cz * 16;
    int s0 = blockIdx.x * 256 + threadIdx.x;   // [0, 4096)
    int t = threadIdx.x;
    __shared__ __align__(16) float sT[16 * NPSP_];   // 31.25 KB
    {
        const float4* src = reinterpret_cast<const float4*>(T0f_l + (size_t)cbase * NPSP_);
        float4* dst = reinterpret_cast<float4*>(sT);
        for (int j = t; j < 16 * NPSP_ / 4; j += 256) dst[j] = src[j];
    }
    __syncthreads();

    int id0 = idx[(size_t)b * S_ + s0];
    int id1 = idx[(size_t)b * S_ + s0 + 4096];
    int id2 = idx[(size_t)b * S_ + s0 + 8192];
    int id3 = idx[(size_t)b * S_ + s0 + 12288];

    double cb = cospi((double)s0 / 8192.0);
    double sb = sinpi((double)s0 / 8192.0);
    double cmd = 1.0, smd = 0.0;
    float cm[16], sm[16];
    cm[0] = 1.0f; sm[0] = 0.0f;
#pragma unroll
    for (int m = 1; m < 16; m++) {
        double nc = cmd * cb - smd * sb;
        double ns = smd * cb + cmd * sb;
        cmd = nc; smd = ns;
        cm[m] = (float)cmd; sm[m] = (float)smd;
    }

    const float* Rb = RECg + ((size_t)b * HID_ + cbase) * RECW_;
    float w0g = Rb[33];
    float* hb = h + (size_t)b * HID_ * S_ + (size_t)cbase * S_;
    double cs0 = 0.0, cs1 = 0.0, cs2 = 0.0, cs3 = 0.0;
#pragma unroll 2
    for (int c = 0; c < 16; c++) {
        const float2* r2 = (const float2*)(Rb + (size_t)c * RECW_);
        const float* tc = sT + c * NPSP_;
        float bias = Rb[(size_t)c * RECW_ + 32];
        float p0 = fmaf(w0g, tc[id0], bias);
        float p1 = fmaf(w0g, tc[id1], bias);
        float p2 = fmaf(w0g, tc[id2], bias);
        float p3 = fmaf(w0g, tc[id3], bias);
        float PA = 0.0f, PB = 0.0f, PC = 0.0f, PD = 0.0f, QB = 0.0f, QD = 0.0f;
#pragma unroll
        for (int mm = 0; mm < 16; mm += 4) {
            float2 q0 = r2[mm], q1 = r2[mm + 1], q2 = r2[mm + 2], q3 = r2[mm + 3];
            PA = fmaf(q0.x, cm[mm], PA);     PA = fmaf(q0.y, sm[mm], PA);
            PB = fmaf(q1.x, cm[mm + 1], PB); PB = fmaf(q1.y, sm[mm + 1], PB);
            QB = fmaf(q1.y, cm[mm + 1], QB); QB = fmaf(-q1.x, sm[mm + 1], QB);
            PC = fmaf(q2.x, cm[mm + 2], PC); PC = fmaf(q2.y, sm[mm + 2], PC);
            PD = fmaf(q3.x, cm[mm + 3], PD); PD = fmaf(q3.y, sm[mm + 3], PD);
            QD = fmaf(q3.y, cm[mm + 3], QD); QD = fmaf(-q3.x, sm[mm + 3], QD);
        }
        float u0 = PA + PC, u1 = PA - PC;
        float w0 = PB + PD, qd = QB - QD;
        float g0 = gelu_f32(p0 + (u0 + w0));
        float g1 = gelu_f32(p1 + (u1 + qd));
        float g2 = gelu_f32(p2 + (u0 - w0));
        float g3 = gelu_f32(p3 + (u1 - qd));
        hb[(size_t)c * S_ + s0]         = g0;
        hb[(size_t)c * S_ + s0 + 4096]  = g1;
        hb[(size_t)c * S_ + s0 + 8192]  = g2;
        hb[(size_t)c * S_ + s0 + 12288] = g3;
        cs0 += (double)g0; cs1 += (double)g1;
        cs2 += (double)g2; cs3 += (double)g3;
    }
    double* sc = sC2 + (size_t)(cz * B_ + b) * S_;
    sc[s0]         = cs0;
    sc[s0 + 4096]  = cs1;
    sc[s0 + 8192]  = cs2;
    sc[s0 + 12288] = cs3;
}

// ---------------------------------------------------------------------------
// Projection: out[b,s] = sum_d h[b,d,s]*pW[d] + pb
// ---------------------------------------------------------------------------
__global__ __launch_bounds__(256) void k_proj(const float* __restrict__ h,
                                              const float* __restrict__ pW,
                                              const float* __restrict__ pb,
                                              float* __restrict__ out) {
    int b = blockIdx.y;
    int s = blockIdx.x * 256 + threadIdx.x;
    const float* hb = h + (size_t)b * HID_ * S_ + s;
    double acc = 0.0;
    for (int d = 0; d < HID_; d++)
        acc += (double)hb[(size_t)d * S_] * (double)pW[d];
    out[(size_t)b * S_ + s] = (float)(acc + (double)pb[0]);
}

extern "C" void kernel_launch(void* const* d_in, const int* in_sizes, int n_in,
                              void* d_out, int out_size, void* d_ws, size_t ws_size,
                              hipStream_t stream) {
    const float* x      = (const float*)d_in[0];
    const float* lift_W = (const float*)d_in[1];
    const float* lift_b = (const float*)d_in[2];
    const float* proj_W = (const float*)d_in[3];
    const float* proj_b = (const float*)d_in[4];
    const float* sp_emb = (const float*)d_in[5];
    const float* sp_W   = (const float*)d_in[6];
    const float* sp_b   = (const float*)d_in[7];
    const float* fr_emb = (const float*)d_in[8];
    const float* fr_W   = (const float*)d_in[9];
    const float* fr_b   = (const float*)d_in[10];
    const float* g_W1   = (const float*)d_in[11];
    const float* g_b1   = (const float*)d_in[12];
    const float* g_W2   = (const float*)d_in[13];
    const float* g_b2   = (const float*)d_in[14];
    const float* mhf_Wr = (const float*)d_in[15];
    const float* mhf_Wi = (const float*)d_in[16];

    char* ws = (char*)d_ws;
    float* h    = (float*)ws;   ws += (size_t)B_ * HID_ * S_ * 4;   // 64 MiB
    double* sC2 = (double*)ws;  ws += (size_t)4 * B_ * S_ * 8;      // 8 MiB (4 slices)
    int* idx    = (int*)ws;     ws += (size_t)B_ * S_ * 4;          // 1 MiB
    double* Xr  = (double*)ws;  ws += (size_t)B_ * HID_ * MODES_ * 8;
    double* Xi  = (double*)ws;  ws += (size_t)B_ * HID_ * MODES_ * 8;
    float* REC  = (float*)ws;   ws += (size_t)B_ * HID_ * RECW_ * 4;
    double* Eb  = (double*)ws;  ws += (size_t)LAYERS_ * B_ * ED_ * 8;
    float* T0f  = (float*)ws;   ws += (size_t)LAYERS_ * HID_ * NPSP_ * 4;  // 500 KiB

    hipMemsetAsync(Eb, 0, (size_t)LAYERS_ * B_ * ED_ * 8, stream);

    dim3 blk(256);
    k_sptab<<<dim3(NPSP_ * HID_ / 256, LAYERS_), blk, 0, stream>>>(sp_emb, sp_W, T0f);
    k_lift<<<dim3(S_ / 256, B_), blk, 0, stream>>>(x, lift_W, lift_b, h, sC2);

    for (int lay = 0; lay < LAYERS_; ++lay) {
        k_hash<<<dim3(S_ / 256, B_), blk, 0, stream>>>(
            sC2, sp_emb + (size_t)lay * NPSP_ * ED_, idx, Eb + (size_t)lay * B_ * ED_);
        k_dft<<<dim3(HID_ * 2, B_), blk, 0, stream>>>(h, Xr, Xi);
        k_gate<<<dim3(B_), blk, 0, stream>>>(
            Xr, Xi,
            mhf_Wr + (size_t)lay * HEADS_ * CH_ * CH_ * MODES_,
            mhf_Wi + (size_t)lay * HEADS_ * CH_ * CH_ * MODES_,
            fr_emb + (size_t)lay * NPFR_ * ED_,
            fr_W + (size_t)lay * ED_ * HID_ * MODES_,
            fr_b + (size_t)lay * HID_ * MODES_,
            Eb + (size_t)lay * B_ * ED_,
            sp_W + (size_t)lay * ED_ * HID_,
            sp_b + (size_t)lay * HID_,
            g_W1 + (size_t)lay * 192 * 64,
            g_b1 + (size_t)lay * 64,
            g_W2 + (size_t)lay * 64 * 3,
            g_b2 + (size_t)lay * 3,
            REC);
        k_recon<<<dim3(S_ / 1024, B_, 4), blk, 0, stream>>>(
            idx, T0f + (size_t)lay * HID_ * NPSP_, REC, h, sC2);
    }

    k_proj<<<dim3(S_ / 256, B_), blk, 0, stream>>>(h, proj_W, proj_b, (float*)d_out);
}